// Round 8
// baseline (127.991 us; speedup 1.0000x reference)
//
#include <hip/hip_runtime.h>

// ---------------------------------------------------------------------------
// RandomForest: 100 trees, depth 5, D=256, B=8192, C=64.
//  * decision = sign(w.x + b); routing reads only node rows 0..15.
//  * prep: X -> split-bf16 (hi/lo) A-swizzled; W -> pre-swizzled LDS image;
//    leaves -> bf16; qcount zeroed.
//  * forest: Z = X.W^T (+bias), 3-MFMA split; global_load_lds B staging;
//    4 blocks/CU (latency cover by occupancy, not register pipelining);
//    register-select traversal; near-ties queued for external fp64 fixup.
// ---------------------------------------------------------------------------

typedef __bf16 bf16;
typedef __attribute__((ext_vector_type(8))) __bf16 bf16x8;
typedef __attribute__((ext_vector_type(4))) float f32x4;

#define NTREES 100
#define NB     8192
#define ND     256
#define NNODES 31
#define NLEAF  32
#define NCLS   64
#define TAU    2.0e-3f
#define QCAP   8192

static __device__ __forceinline__ void gload16(const void* g, void* l) {
    __builtin_amdgcn_global_load_lds(
        (const __attribute__((address_space(1))) void*)g,
        (__attribute__((address_space(3))) void*)l, 16, 0, 0);
}

// ---- K1: prep. blocks 0..1023: X split. 1024..1223: W image. 1224..2023: leaves.
__global__ void prep(const float* __restrict__ x, const float* __restrict__ wf,
                     const float* __restrict__ lv,
                     bf16* __restrict__ xh, bf16* __restrict__ xl,
                     bf16* __restrict__ wimg, bf16* __restrict__ lv16,
                     unsigned int* __restrict__ qcount) {
    if (blockIdx.x == 0 && threadIdx.x == 0) *qcount = 0;
    if (blockIdx.x < 1024) {
        int i = blockIdx.x * 256 + threadIdx.x;       // 0 .. 262143
        int m  = i & 15;
        int dq = (i >> 4) & 31;
        int g  = i >> 9;
        const float* src = x + (size_t)(g * 16 + m) * ND + dq * 8;
        bf16x8 h8, l8;
#pragma unroll
        for (int e = 0; e < 8; ++e) {
            float f = src[e];
            bf16 h = (bf16)f;
            h8[e] = h;
            l8[e] = (bf16)(f - (float)h);
        }
        *(bf16x8*)(xh + (size_t)i * 8) = h8;
        *(bf16x8*)(xl + (size_t)i * 8) = l8;
    } else if (blockIdx.x < 1224) {
        int i = (blockIdx.x - 1024) * 256 + threadIdx.x;  // 0..51199
        int oct = i & 31;            // k-octet 0..31
        int row = (i >> 5) & 63;     // B row 0..63
        int tg  = i >> 11;           // tree group 0..24
        int tree = tg * 4 + (row >> 4), node = row & 15;
        const float* src = wf + ((size_t)tree * NNODES + node) * ND + oct * 8;
        bf16x8 h8, l8;
#pragma unroll
        for (int e = 0; e < 8; ++e) {
            float f = src[e];
            bf16 h = (bf16)f;
            h8[e] = h;
            l8[e] = (bf16)(f - (float)h);
        }
        int kc = oct >> 4, c = oct & 15, cp = c ^ (row & 7);
        size_t b = (size_t)tg * 32768 + (size_t)kc * 16384 + row * 128 + cp * 8;
        *(bf16x8*)(wimg + b)        = h8;   // hi half
        *(bf16x8*)(wimg + b + 8192) = l8;   // lo half
    } else {
        int i = (blockIdx.x - 1224) * 256 + threadIdx.x;  // 0..204799
        lv16[i] = (bf16)lv[i];
    }
}

// ---- K2: GEMM + traversal ----------------------------------------------------
// block: 256 samples x 4 trees. XCD-swizzled: xcd owns mg in {4*xcd..4*xcd+3}.
__global__ __launch_bounds__(256, 4) void forest_all(
    const bf16* __restrict__ xh, const bf16* __restrict__ xl,
    const bf16* __restrict__ wimg,
    const float* __restrict__ bias,    // [100][31]
    unsigned char* __restrict__ idxb,  // [8192][100]
    unsigned int* __restrict__ qcount, unsigned int* __restrict__ queue)
{
    __shared__ char lds[32768];            // B (hi 16KB | lo 16KB); scratch overlays
    bf16*  Wh  = (bf16*)lds;
    bf16*  Wl  = (bf16*)(lds + 16384);
    float* scr = (float*)lds;              // [4 waves][64][20] after K-loop

    const int tid  = threadIdx.x;
    const int wave = tid >> 6;
    const int lane = tid & 63;
    const int m    = lane & 15;
    const int q    = lane >> 4;

    const int lin  = blockIdx.x + gridDim.x * blockIdx.y;   // 0..799
    const int xcd  = lin & 7;
    const int slot = lin >> 3;             // 0..99
    const int mg   = xcd * 4 + (slot / 25);
    const int tg   = slot % 25;

    float biasv[4];
#pragma unroll
    for (int ni = 0; ni < 4; ++ni)
        biasv[ni] = bias[(size_t)(tg * 4 + ni) * NNODES + m];

    f32x4 acc[4][4];
#pragma unroll
    for (int mi = 0; mi < 4; ++mi)
#pragma unroll
        for (int ni = 0; ni < 4; ++ni)
            acc[mi][ni] = (f32x4){0.f, 0.f, 0.f, 0.f};

    size_t abase[4];
#pragma unroll
    for (int mi = 0; mi < 4; ++mi)
        abase[mi] = (size_t)(mg * 16 + wave * 4 + mi) * 4096 + lane * 8;

    const bf16* wsrc = wimg + (size_t)tg * 32768;

#pragma unroll
    for (int kc = 0; kc < 2; ++kc) {
        if (kc) __syncthreads();           // previous half's B fully consumed
        // ---- stage B half: 32KB via global_load_lds width-16 (8 insts/wave)
#pragma unroll
        for (int j = 0; j < 8; ++j) {
            int idx = j * 256 + tid;       // 0..2047 16B chunks
            gload16(wsrc + (size_t)kc * 16384 + idx * 8, lds + idx * 16);
        }
        __syncthreads();

#pragma unroll
        for (int kk = 0; kk < 4; ++kk) {
            bf16x8 ah[4], al[4];
#pragma unroll
            for (int mi = 0; mi < 4; ++mi) {
                size_t off = abase[mi] + (size_t)(kc * 16 + kk * 4) * 128;
                ah[mi] = *(const bf16x8*)(xh + off);
                al[mi] = *(const bf16x8*)(xl + off);
            }
#pragma unroll
            for (int ni = 0; ni < 4; ++ni) {
                const int n    = ni * 16 + m;
                const int cidx = (4 * kk + q) ^ (m & 7);
                bf16x8 bh = *(const bf16x8*)(Wh + n * 128 + cidx * 8);
                bf16x8 bl = *(const bf16x8*)(Wl + n * 128 + cidx * 8);
#pragma unroll
                for (int mi = 0; mi < 4; ++mi) {
                    acc[mi][ni] = __builtin_amdgcn_mfma_f32_16x16x32_bf16(al[mi], bh, acc[mi][ni], 0, 0, 0);
                    acc[mi][ni] = __builtin_amdgcn_mfma_f32_16x16x32_bf16(ah[mi], bl, acc[mi][ni], 0, 0, 0);
                    acc[mi][ni] = __builtin_amdgcn_mfma_f32_16x16x32_bf16(ah[mi], bh, acc[mi][ni], 0, 0, 0);
                }
            }
        }
    }
    __syncthreads();   // all waves done with B; LDS becomes per-wave scratch

    // ---- epilogue: per-wave transpose via LDS, register-select traversal
    float* ws_ = scr + wave * 1280;                // 64 rows x 20 floats
    const int s_l = wave * 64 + lane;
    const int sg  = mg * 256 + s_l;
    unsigned int pk = 0;
#pragma unroll
    for (int ni = 0; ni < 4; ++ni) {
        // D layout: row = q*4+r (sample within 16), col = m (node)
#pragma unroll
        for (int mi = 0; mi < 4; ++mi)
#pragma unroll
            for (int r = 0; r < 4; ++r)
                ws_[(mi * 16 + q * 4 + r) * 20 + m] = acc[mi][ni][r] + biasv[ni];
        // wave-private scratch; in-wave LDS ordering via lgkmcnt (no barrier)
        f32x4 z0 = *(f32x4*)&ws_[lane * 20];
        f32x4 z1 = *(f32x4*)&ws_[lane * 20 + 4];
        f32x4 z2 = *(f32x4*)&ws_[lane * 20 + 8];
        f32x4 z3 = *(f32x4*)&ws_[lane * 20 + 12];
        float z[16] = {z0[0], z0[1], z0[2], z0[3], z1[0], z1[1], z1[2], z1[3],
                       z2[0], z2[1], z2[2], z2[3], z3[0], z3[1], z3[2], z3[3]};
        float a0 = z[0];
        bool d0 = a0 <= 0.f;
        float a1 = d0 ? z[1] : z[0];
        bool d1 = a1 <= 0.f;
        float a2 = d0 ? (d1 ? z[3] : z[2]) : (d1 ? z[1] : z[0]);
        bool d2 = a2 <= 0.f;
        float m0 = d2 ? z[1] : z[0], m1 = d2 ? z[3] : z[2];
        float m2 = d2 ? z[5] : z[4], m3 = d2 ? z[7] : z[6];
        float p0 = d1 ? m1 : m0, p1 = d1 ? m3 : m2;
        float a3 = d0 ? p1 : p0;
        bool d3 = a3 <= 0.f;
        float n0 = d3 ? z[1] : z[0],  n1 = d3 ? z[3] : z[2];
        float n2 = d3 ? z[5] : z[4],  n3 = d3 ? z[7] : z[6];
        float n4 = d3 ? z[9] : z[8],  n5 = d3 ? z[11] : z[10];
        float n6 = d3 ? z[13] : z[12], n7 = d3 ? z[15] : z[14];
        float q0 = d2 ? n1 : n0, q1 = d2 ? n3 : n2;
        float q2 = d2 ? n5 : n4, q3 = d2 ? n7 : n6;
        float r0 = d1 ? q1 : q0, r1 = d1 ? q3 : q2;
        float a4 = d0 ? r1 : r0;
        bool d4 = a4 <= 0.f;
        int leaf = ((int)d0 << 4) | ((int)d1 << 3) | ((int)d2 << 2)
                 | ((int)d3 << 1) | (int)d4;
        pk |= (unsigned)leaf << (8 * ni);
        float mn = fminf(fminf(fminf(fabsf(a0), fabsf(a1)),
                               fminf(fabsf(a2), fabsf(a3))), fabsf(a4));
        if (mn < TAU) {
            unsigned int pos = atomicAdd(qcount, 1u);
            if (pos < QCAP)
                queue[pos] = ((unsigned)(tg * 4 + ni) << 13) | (unsigned)sg;
        }
    }
    *(unsigned int*)(idxb + (size_t)sg * NTREES + tg * 4) = pk;
}

// ---- K3: exact fp64 re-traversal of queued near-ties ------------------------
__global__ void fixup_kernel(const float* __restrict__ x, const float* __restrict__ wf,
                             const float* __restrict__ bias,
                             const unsigned int* __restrict__ qcount,
                             const unsigned int* __restrict__ queue,
                             unsigned char* __restrict__ idxb) {
    const int wid  = (blockIdx.x * 256 + threadIdx.x) >> 6;   // global wave id
    const int lane = threadIdx.x & 63;
    unsigned int n = *qcount;
    if (n > QCAP) n = QCAP;
    for (unsigned int it = wid; it < n; it += 256) {
        unsigned int e = queue[it];
        int t = e >> 13, s = e & 8191;
        const float* xr = x + (size_t)s * ND;
        float4 xv = *(const float4*)(xr + lane * 4);
        int node = 0;
        for (int lvl = 0; lvl < 5; ++lvl) {
            const float* wr = wf + ((size_t)t * NNODES + node) * ND;
            float4 wv = *(const float4*)(wr + lane * 4);
            double zz = (double)xv.x * wv.x + (double)xv.y * wv.y
                      + (double)xv.z * wv.z + (double)xv.w * wv.w;
#pragma unroll
            for (int o = 32; o > 0; o >>= 1) zz += __shfl_xor(zz, o);
            zz += (double)bias[t * NNODES + node];
            node = 2 * node + (zz <= 0.0 ? 1 : 0);
        }
        if (lane == 0) idxb[(size_t)s * NTREES + t] = (unsigned char)node;
    }
}

// ---- K4: leaf gather (bf16 leaves) + forest mean ----------------------------
__global__ void leaf_gather(const unsigned char* __restrict__ idxb,
                            const bf16* __restrict__ lv16,
                            float* __restrict__ out) {
    const int wave = threadIdx.x >> 6;
    const int lane = threadIdx.x & 63;
    const int s = blockIdx.x * 4 + wave;
    unsigned int rw = 0;
    if (lane < 25) rw = *(const unsigned int*)(idxb + (size_t)s * NTREES + lane * 4);
    float acc = 0.f;
#pragma unroll 10
    for (int t = 0; t < NTREES; ++t) {
        unsigned int wrd = __shfl(rw, t >> 2);
        int li = (wrd >> ((t & 3) * 8)) & 255;
        acc += (float)lv16[((size_t)t * NLEAF + li) * NCLS + lane];
    }
    out[(size_t)s * NCLS + lane] = acc * 0.01f;
}

// ---------------------------------------------------------------------------
extern "C" void kernel_launch(void* const* d_in, const int* in_sizes, int n_in,
                              void* d_out, int out_size, void* d_ws, size_t ws_size,
                              hipStream_t stream) {
    const float* x  = (const float*)d_in[0];   // [8192,256]
    const float* nw = (const float*)d_in[1];   // [100,31,256]
    const float* nb = (const float*)d_in[2];   // [100,31]
    const float* lv = (const float*)d_in[3];   // [100,32,64]
    float* out = (float*)d_out;

    char* ws = (char*)d_ws;
    bf16* xh   = (bf16*)(ws + 0);                           // 4,194,304
    bf16* xl   = (bf16*)(ws + 4194304);                     // 4,194,304
    bf16* wimg = (bf16*)(ws + 8388608);                     // 1,638,400
    unsigned char* idxb = (unsigned char*)(ws + 10027008);  //   819,200
    bf16* lv16 = (bf16*)(ws + 10846208);                    //   409,600
    unsigned int* qcount = (unsigned int*)(ws + 11255808);  //        16
    unsigned int* queue  = (unsigned int*)(ws + 11255824);  //    32,768
    if (ws_size < (size_t)11288592) return;

    prep<<<2024, 256, 0, stream>>>(x, nw, lv, xh, xl, wimg, lv16, qcount);
    forest_all<<<dim3(25, 32), 256, 0, stream>>>(
        xh, xl, wimg, nb, idxb, qcount, queue);
    fixup_kernel<<<64, 256, 0, stream>>>(x, nw, nb, qcount, queue, idxb);
    leaf_gather<<<NB / 4, 256, 0, stream>>>(idxb, lv16, out);
}

// Round 9
// 108.899 us; speedup vs baseline: 1.1753x; 1.1753x over previous
//
#include <hip/hip_runtime.h>

// ---------------------------------------------------------------------------
// RandomForest: 100 trees, depth 5, D=256, B=8192, C=64.
//  * decision = sign(w.x + b); routing reads only node rows 0..15.
//  * prep: X -> split-bf16 (hi/lo) A-swizzled; W -> pre-swizzled LDS image
//    (13 groups x 8 trees, 4 zero dummy trees); leaves -> bf16.
//  * forest: Nt=128 (8 trees/block), double-buffered quarter-K B staging via
//    global_load_lds; 3-MFMA split; register-select traversal; near-ties
//    queued for external fp64 fixup. bounds(256,2): generous VGPRs (R6/R8
//    showed the 64-VGPR squeeze at bounds-4 serializes A loads).
// ---------------------------------------------------------------------------

typedef __bf16 bf16;
typedef __attribute__((ext_vector_type(8))) __bf16 bf16x8;
typedef __attribute__((ext_vector_type(4))) float f32x4;

#define NTREES 100
#define NB     8192
#define ND     256
#define NNODES 31
#define NLEAF  32
#define NCLS   64
#define TAU    2.0e-3f
#define QCAP   8192

static __device__ __forceinline__ void gload16(const void* g, void* l) {
    __builtin_amdgcn_global_load_lds(
        (const __attribute__((address_space(1))) void*)g,
        (__attribute__((address_space(3))) void*)l, 16, 0, 0);
}

// ---- K1: prep ---------------------------------------------------------------
// blocks 0..1023: X split (layout: i = g*4096 + dq*128 + m*8 + e).
// blocks 1024..1231: W image, 13 tg x [4 kq x (hi 16KB | lo 16KB)];
//   within: row*64 + (oct^(row&7))*8, oct = k-octet within quarter.
// blocks 1232..2031: leaves -> bf16.
__global__ void prep(const float* __restrict__ x, const float* __restrict__ wf,
                     const float* __restrict__ lv,
                     bf16* __restrict__ xh, bf16* __restrict__ xl,
                     bf16* __restrict__ wimg, bf16* __restrict__ lv16,
                     unsigned int* __restrict__ qcount) {
    if (blockIdx.x == 0 && threadIdx.x == 0) *qcount = 0;
    if (blockIdx.x < 1024) {
        int i = blockIdx.x * 256 + threadIdx.x;       // 0 .. 262143
        int m  = i & 15;
        int dq = (i >> 4) & 31;
        int g  = i >> 9;
        const float* src = x + (size_t)(g * 16 + m) * ND + dq * 8;
        bf16x8 h8, l8;
#pragma unroll
        for (int e = 0; e < 8; ++e) {
            float f = src[e];
            bf16 h = (bf16)f;
            h8[e] = h;
            l8[e] = (bf16)(f - (float)h);
        }
        *(bf16x8*)(xh + (size_t)i * 8) = h8;
        *(bf16x8*)(xl + (size_t)i * 8) = l8;
    } else if (blockIdx.x < 1232) {
        int i = (blockIdx.x - 1024) * 256 + threadIdx.x;  // 0..53247
        int oct_g = i & 31;          // global k-octet 0..31
        int row   = (i >> 5) & 127;  // B row 0..127
        int tg    = i >> 12;         // tree group 0..12
        int tree  = tg * 8 + (row >> 4), node = row & 15;
        bf16x8 h8, l8;
        if (tree < NTREES) {
            const float* src = wf + ((size_t)tree * NNODES + node) * ND + oct_g * 8;
#pragma unroll
            for (int e = 0; e < 8; ++e) {
                float f = src[e];
                bf16 h = (bf16)f;
                h8[e] = h;
                l8[e] = (bf16)(f - (float)h);
            }
        } else {
#pragma unroll
            for (int e = 0; e < 8; ++e) { h8[e] = (bf16)0.f; l8[e] = (bf16)0.f; }
        }
        int kq = oct_g >> 3, oct = oct_g & 7, cp = oct ^ (row & 7);
        size_t b = (size_t)tg * 65536 + (size_t)kq * 16384 + row * 64 + cp * 8;
        *(bf16x8*)(wimg + b)        = h8;   // hi
        *(bf16x8*)(wimg + b + 8192) = l8;   // lo
    } else {
        int i = (blockIdx.x - 1232) * 256 + threadIdx.x;  // 0..204799
        lv16[i] = (bf16)lv[i];
    }
}

// ---- K2: GEMM + traversal ----------------------------------------------------
// block: 256 samples x 8 trees (128 cols). 4 waves, each M=64, N=128.
__global__ __launch_bounds__(256, 2) void forest_all(
    const bf16* __restrict__ xh, const bf16* __restrict__ xl,
    const bf16* __restrict__ wimg,
    const float* __restrict__ bias,    // [100][31]
    unsigned char* __restrict__ idxb,  // [8192][100]
    unsigned int* __restrict__ qcount, unsigned int* __restrict__ queue)
{
    __shared__ char lds[65536];            // two 32KB B buffers; scr overlays buf0
    float* scr = (float*)lds;              // [4 waves][64][20] after K-loop

    const int tid  = threadIdx.x;
    const int wave = tid >> 6;
    const int lane = tid & 63;
    const int m    = lane & 15;
    const int q    = lane >> 4;

    const int lin  = blockIdx.x + gridDim.x * blockIdx.y;   // 0..415
    const int xcd  = lin & 7;
    const int slot = lin >> 3;             // 0..51
    const int mg   = xcd * 4 + (slot / 13);
    const int tg   = slot % 13;            // tree-group of 8 (tg 12: 4 real)

    float biasv[8];
#pragma unroll
    for (int ni = 0; ni < 8; ++ni) {
        int tree = tg * 8 + ni;
        biasv[ni] = (tree < NTREES) ? bias[(size_t)tree * NNODES + m] : 0.f;
    }

    f32x4 acc[4][8];
#pragma unroll
    for (int mi = 0; mi < 4; ++mi)
#pragma unroll
        for (int ni = 0; ni < 8; ++ni)
            acc[mi][ni] = (f32x4){0.f, 0.f, 0.f, 0.f};

    size_t abase[4];
#pragma unroll
    for (int mi = 0; mi < 4; ++mi)
        abase[mi] = (size_t)(mg * 16 + wave * 4 + mi) * 4096 + lane * 8;

    const bf16* wsrc = wimg + (size_t)tg * 65536;

    // ---- stage kq=0 into buf0, then loop with 1-ahead async staging
#pragma unroll
    for (int j = 0; j < 8; ++j) {
        int idx = j * 256 + tid;           // 2048 16B chunks = 32KB
        gload16(wsrc + idx * 8, lds + idx * 16);
    }
    __syncthreads();

    // A prefetch pipeline (cur/nxt), kk = 0..7 global
    bf16x8 cah[4], cal[4], nah[4], nal[4];
#pragma unroll
    for (int mi = 0; mi < 4; ++mi) {
        cah[mi] = *(const bf16x8*)(xh + abase[mi]);
        cal[mi] = *(const bf16x8*)(xl + abase[mi]);
    }

#pragma unroll
    for (int kq = 0; kq < 4; ++kq) {
        const char* bufc = lds + (kq & 1) * 32768;
        if (kq < 3) {                      // async-stage next quarter
            char* bufn = lds + ((kq + 1) & 1) * 32768;
#pragma unroll
            for (int j = 0; j < 8; ++j) {
                int idx = j * 256 + tid;
                gload16(wsrc + (size_t)(kq + 1) * 16384 + idx * 8, bufn + idx * 16);
            }
        }
#pragma unroll
        for (int kkq = 0; kkq < 2; ++kkq) {
            const int kk = kq * 2 + kkq;
            if (kk < 7) {                  // prefetch next A batch
#pragma unroll
                for (int mi = 0; mi < 4; ++mi) {
                    nah[mi] = *(const bf16x8*)(xh + abase[mi] + (kk + 1) * 512);
                    nal[mi] = *(const bf16x8*)(xl + abase[mi] + (kk + 1) * 512);
                }
            }
#pragma unroll
            for (int ni = 0; ni < 8; ++ni) {
                const int n  = ni * 16 + m;
                const int cp = (kkq * 4 + q) ^ (m & 7);
                bf16x8 bh = *(const bf16x8*)((const bf16*)bufc + n * 64 + cp * 8);
                bf16x8 bl = *(const bf16x8*)((const bf16*)bufc + 8192 + n * 64 + cp * 8);
#pragma unroll
                for (int mi = 0; mi < 4; ++mi) {
                    acc[mi][ni] = __builtin_amdgcn_mfma_f32_16x16x32_bf16(cal[mi], bh, acc[mi][ni], 0, 0, 0);
                    acc[mi][ni] = __builtin_amdgcn_mfma_f32_16x16x32_bf16(cah[mi], bl, acc[mi][ni], 0, 0, 0);
                    acc[mi][ni] = __builtin_amdgcn_mfma_f32_16x16x32_bf16(cah[mi], bh, acc[mi][ni], 0, 0, 0);
                }
            }
#pragma unroll
            for (int mi = 0; mi < 4; ++mi) { cah[mi] = nah[mi]; cal[mi] = nal[mi]; }
        }
        __syncthreads();   // next buffer staged AND current fully consumed
    }

    // ---- epilogue: per-wave transpose via LDS, register-select traversal
    float* ws_ = scr + wave * 1280;                // 64 rows x 20 floats
    const int s_l = wave * 64 + lane;
    const int sg  = mg * 256 + s_l;
    unsigned int pk0 = 0, pk1 = 0;
#pragma unroll
    for (int ni = 0; ni < 8; ++ni) {
        // D layout: row = q*4+r (sample within 16), col = m (node)
#pragma unroll
        for (int mi = 0; mi < 4; ++mi)
#pragma unroll
            for (int r = 0; r < 4; ++r)
                ws_[(mi * 16 + q * 4 + r) * 20 + m] = acc[mi][ni][r] + biasv[ni];
        f32x4 z0 = *(f32x4*)&ws_[lane * 20];
        f32x4 z1 = *(f32x4*)&ws_[lane * 20 + 4];
        f32x4 z2 = *(f32x4*)&ws_[lane * 20 + 8];
        f32x4 z3 = *(f32x4*)&ws_[lane * 20 + 12];
        float z[16] = {z0[0], z0[1], z0[2], z0[3], z1[0], z1[1], z1[2], z1[3],
                       z2[0], z2[1], z2[2], z2[3], z3[0], z3[1], z3[2], z3[3]};
        float a0 = z[0];
        bool d0 = a0 <= 0.f;
        float a1 = d0 ? z[1] : z[0];
        bool d1 = a1 <= 0.f;
        float a2 = d0 ? (d1 ? z[3] : z[2]) : (d1 ? z[1] : z[0]);
        bool d2 = a2 <= 0.f;
        float m0 = d2 ? z[1] : z[0], m1 = d2 ? z[3] : z[2];
        float m2 = d2 ? z[5] : z[4], m3 = d2 ? z[7] : z[6];
        float p0 = d1 ? m1 : m0, p1 = d1 ? m3 : m2;
        float a3 = d0 ? p1 : p0;
        bool d3 = a3 <= 0.f;
        float n0 = d3 ? z[1] : z[0],  n1 = d3 ? z[3] : z[2];
        float n2 = d3 ? z[5] : z[4],  n3 = d3 ? z[7] : z[6];
        float n4 = d3 ? z[9] : z[8],  n5 = d3 ? z[11] : z[10];
        float n6 = d3 ? z[13] : z[12], n7 = d3 ? z[15] : z[14];
        float q0 = d2 ? n1 : n0, q1 = d2 ? n3 : n2;
        float q2 = d2 ? n5 : n4, q3 = d2 ? n7 : n6;
        float r0 = d1 ? q1 : q0, r1 = d1 ? q3 : q2;
        float a4 = d0 ? r1 : r0;
        bool d4 = a4 <= 0.f;
        int leaf = ((int)d0 << 4) | ((int)d1 << 3) | ((int)d2 << 2)
                 | ((int)d3 << 1) | (int)d4;
        if (ni < 4) pk0 |= (unsigned)leaf << (8 * ni);
        else        pk1 |= (unsigned)leaf << (8 * (ni - 4));
        float mn = fminf(fminf(fminf(fabsf(a0), fabsf(a1)),
                               fminf(fabsf(a2), fabsf(a3))), fabsf(a4));
        const int tree = tg * 8 + ni;
        if (tree < NTREES && mn < TAU) {   // dummy trees (z==0) must not enqueue
            unsigned int pos = atomicAdd(qcount, 1u);
            if (pos < QCAP)
                queue[pos] = ((unsigned)tree << 13) | (unsigned)sg;
        }
    }
    unsigned char* dst = idxb + (size_t)sg * NTREES + tg * 8;
    *(unsigned int*)dst = pk0;
    if (tg < 12) *(unsigned int*)(dst + 4) = pk1;
}

// ---- K3: exact fp64 re-traversal of queued near-ties ------------------------
__global__ void fixup_kernel(const float* __restrict__ x, const float* __restrict__ wf,
                             const float* __restrict__ bias,
                             const unsigned int* __restrict__ qcount,
                             const unsigned int* __restrict__ queue,
                             unsigned char* __restrict__ idxb) {
    const int wid  = (blockIdx.x * 256 + threadIdx.x) >> 6;   // global wave id
    const int lane = threadIdx.x & 63;
    unsigned int n = *qcount;
    if (n > QCAP) n = QCAP;
    for (unsigned int it = wid; it < n; it += 256) {
        unsigned int e = queue[it];
        int t = e >> 13, s = e & 8191;
        const float* xr = x + (size_t)s * ND;
        float4 xv = *(const float4*)(xr + lane * 4);
        int node = 0;
        for (int lvl = 0; lvl < 5; ++lvl) {
            const float* wr = wf + ((size_t)t * NNODES + node) * ND;
            float4 wv = *(const float4*)(wr + lane * 4);
            double zz = (double)xv.x * wv.x + (double)xv.y * wv.y
                      + (double)xv.z * wv.z + (double)xv.w * wv.w;
#pragma unroll
            for (int o = 32; o > 0; o >>= 1) zz += __shfl_xor(zz, o);
            zz += (double)bias[t * NNODES + node];
            node = 2 * node + (zz <= 0.0 ? 1 : 0);
        }
        if (lane == 0) idxb[(size_t)s * NTREES + t] = (unsigned char)node;
    }
}

// ---- K4: leaf gather (bf16 leaves) + forest mean ----------------------------
__global__ void leaf_gather(const unsigned char* __restrict__ idxb,
                            const bf16* __restrict__ lv16,
                            float* __restrict__ out) {
    const int wave = threadIdx.x >> 6;
    const int lane = threadIdx.x & 63;
    const int s = blockIdx.x * 4 + wave;
    unsigned int rw = 0;
    if (lane < 25) rw = *(const unsigned int*)(idxb + (size_t)s * NTREES + lane * 4);
    float acc = 0.f;
#pragma unroll 10
    for (int t = 0; t < NTREES; ++t) {
        unsigned int wrd = __shfl(rw, t >> 2);
        int li = (wrd >> ((t & 3) * 8)) & 255;
        acc += (float)lv16[((size_t)t * NLEAF + li) * NCLS + lane];
    }
    out[(size_t)s * NCLS + lane] = acc * 0.01f;
}

// ---------------------------------------------------------------------------
extern "C" void kernel_launch(void* const* d_in, const int* in_sizes, int n_in,
                              void* d_out, int out_size, void* d_ws, size_t ws_size,
                              hipStream_t stream) {
    const float* x  = (const float*)d_in[0];   // [8192,256]
    const float* nw = (const float*)d_in[1];   // [100,31,256]
    const float* nb = (const float*)d_in[2];   // [100,31]
    const float* lv = (const float*)d_in[3];   // [100,32,64]
    float* out = (float*)d_out;

    char* ws = (char*)d_ws;
    bf16* xh   = (bf16*)(ws + 0);                           // 4,194,304
    bf16* xl   = (bf16*)(ws + 4194304);                     // 4,194,304
    bf16* wimg = (bf16*)(ws + 8388608);                     // 1,703,936
    unsigned char* idxb = (unsigned char*)(ws + 10092544);  //   819,200
    bf16* lv16 = (bf16*)(ws + 10911744);                    //   409,600
    unsigned int* qcount = (unsigned int*)(ws + 11321344);  //        16
    unsigned int* queue  = (unsigned int*)(ws + 11321360);  //    32,768
    if (ws_size < (size_t)11354128) return;

    prep<<<2032, 256, 0, stream>>>(x, nw, lv, xh, xl, wimg, lv16, qcount);
    forest_all<<<dim3(13, 32), 256, 0, stream>>>(
        xh, xl, wimg, nb, idxb, qcount, queue);
    fixup_kernel<<<64, 256, 0, stream>>>(x, nw, nb, qcount, queue, idxb);
    leaf_gather<<<NB / 4, 256, 0, stream>>>(idxb, lv16, out);
}